// Round 1
// baseline (203.933 us; speedup 1.0000x reference)
//
#include <hip/hip_runtime.h>

// AnomalyAttention forward, MI355X gfx950.
// B=8, N=1024, D=1024. Out = [Z (8*1024*1024 f32), P (8*1024*1024 f32)].
// Workspace usage ~90.3 MB (with reuse).

typedef __attribute__((ext_vector_type(8))) short bf16x8;
typedef __attribute__((ext_vector_type(4))) float f32x4;

#define DI __device__ __forceinline__

constexpr int  SEQ   = 1024;
constexpr int  BATCH = 8;
constexpr long NN    = 1024L * 1024L;   // N*N
constexpr long ND    = 1024L * 1024L;   // N*D

DI unsigned short f2bf(float f) {  // round-to-nearest-even f32 -> bf16 bits
    unsigned int u = __float_as_uint(f);
    u = u + 0x7fffu + ((u >> 16) & 1u);
    return (unsigned short)(u >> 16);
}

// ---------------------------------------------------------------------------
// GEMM: C[M,N] = A[M,K] * Bt[N,K]^T, all dims 1024, bf16 in, fp32 acc.
// 128x128 tile, BK=32, 4 waves (2x2), 4x4 16x16x32 MFMA frags per wave.
// OUT_F32=0: bf16 out; OUT_F32=1: f32 out * scale.
// ---------------------------------------------------------------------------
template <int OUT_F32>
__global__ __launch_bounds__(256)
void gemm_bt(const unsigned short* __restrict__ A,
             const unsigned short* __restrict__ Bt,
             void* __restrict__ Cout,
             long strideA, long strideB, long strideC, float scale)
{
    const unsigned short* Ab = A  + (long)blockIdx.z * strideA;
    const unsigned short* Bb = Bt + (long)blockIdx.z * strideB;

    __shared__ unsigned short sA[128 * 32];
    __shared__ unsigned short sB[128 * 32];

    const int tid  = threadIdx.x;
    const int wave = tid >> 6;
    const int lane = tid & 63;
    const int wm   = wave >> 1;   // 0..1
    const int wn   = wave & 1;    // 0..1
    const int bm   = blockIdx.x * 128;
    const int bn   = blockIdx.y * 128;

    f32x4 acc[4][4];
#pragma unroll
    for (int m = 0; m < 4; ++m)
#pragma unroll
        for (int n = 0; n < 4; ++n) acc[m][n] = (f32x4){0.f, 0.f, 0.f, 0.f};

    // staging: thread t loads 16B; row = t>>2 (64 rows/issue), chunk = t&3
    const int  srow   = tid >> 2;
    const int  schunk = tid & 3;
    const long arow0  = (long)(bm + srow) * 1024 + schunk * 8;
    const long brow0  = (long)(bn + srow) * 1024 + schunk * 8;
    unsigned short* lA0 = sA + wave * 512;          // wave-uniform LDS bases
    unsigned short* lA1 = sA + 2048 + wave * 512;
    unsigned short* lB0 = sB + wave * 512;
    unsigned short* lB1 = sB + 2048 + wave * 512;

    // fragment LDS element offsets: row*(32) + (lane>>4)*8
    const int fra = (wm * 64 + (lane & 15)) * 32 + (lane >> 4) * 8;
    const int frb = (wn * 64 + (lane & 15)) * 32 + (lane >> 4) * 8;

    for (int k0 = 0; k0 < 1024; k0 += 32) {
        const unsigned short* ga0 = Ab + arow0 + k0;
        const unsigned short* gb0 = Bb + brow0 + k0;
        __builtin_amdgcn_global_load_lds(
            (const __attribute__((address_space(1))) void*)ga0,
            (__attribute__((address_space(3))) void*)lA0, 16, 0, 0);
        __builtin_amdgcn_global_load_lds(
            (const __attribute__((address_space(1))) void*)(ga0 + 64 * 1024),
            (__attribute__((address_space(3))) void*)lA1, 16, 0, 0);
        __builtin_amdgcn_global_load_lds(
            (const __attribute__((address_space(1))) void*)gb0,
            (__attribute__((address_space(3))) void*)lB0, 16, 0, 0);
        __builtin_amdgcn_global_load_lds(
            (const __attribute__((address_space(1))) void*)(gb0 + 64 * 1024),
            (__attribute__((address_space(3))) void*)lB1, 16, 0, 0);
        __syncthreads();

        bf16x8 af[4], bfv[4];
#pragma unroll
        for (int m = 0; m < 4; ++m)
            af[m] = *(const bf16x8*)(sA + fra + m * 512);
#pragma unroll
        for (int n = 0; n < 4; ++n)
            bfv[n] = *(const bf16x8*)(sB + frb + n * 512);
#pragma unroll
        for (int m = 0; m < 4; ++m)
#pragma unroll
            for (int n = 0; n < 4; ++n)
                acc[m][n] = __builtin_amdgcn_mfma_f32_16x16x32_bf16(
                    af[m], bfv[n], acc[m][n], 0, 0, 0);
        __syncthreads();
    }

    // C/D layout (verified m89): col = lane&15, row = (lane>>4)*4 + r
    const int crow = wm * 64 + (lane >> 4) * 4;
    const int ccol = wn * 64 + (lane & 15);
    if (OUT_F32) {
        float* C = (float*)Cout + (long)blockIdx.z * strideC;
#pragma unroll
        for (int m = 0; m < 4; ++m)
#pragma unroll
            for (int n = 0; n < 4; ++n)
#pragma unroll
                for (int r = 0; r < 4; ++r)
                    C[(long)(bm + crow + m * 16 + r) * 1024 + (bn + ccol + n * 16)] =
                        acc[m][n][r] * scale;
    } else {
        unsigned short* C = (unsigned short*)Cout + (long)blockIdx.z * strideC;
#pragma unroll
        for (int m = 0; m < 4; ++m)
#pragma unroll
            for (int n = 0; n < 4; ++n)
#pragma unroll
                for (int r = 0; r < 4; ++r)
                    C[(long)(bm + crow + m * 16 + r) * 1024 + (bn + ccol + n * 16)] =
                        f2bf(acc[m][n][r]);
    }
}

// ---------------------------------------------------------------------------
// elementwise / helper kernels
// ---------------------------------------------------------------------------
__global__ void cvt_x_bf16(const float* __restrict__ in, unsigned short* __restrict__ out)
{
    long i = ((long)blockIdx.x * 256 + threadIdx.x) * 4;
    float4 v = *(const float4*)(in + i);
    ushort4 o;
    o.x = f2bf(v.x); o.y = f2bf(v.y); o.z = f2bf(v.z); o.w = f2bf(v.w);
    *(ushort4*)(out + i) = o;
}

// W [D,D] f32 -> WT [D,D] bf16 with WT[n][k] = W[k][n]; 64x64 LDS tiles
__global__ void wt_cvt_transpose(const float* __restrict__ W, unsigned short* __restrict__ WT)
{
    __shared__ float s[64][65];
    const int tr = blockIdx.x * 64, tc = blockIdx.y * 64;
    const int t = threadIdx.x;
    const int r = t >> 4, c4 = (t & 15) * 4;
#pragma unroll
    for (int rr = r; rr < 64; rr += 16) {
        float4 v = *(const float4*)(W + (long)(tr + rr) * 1024 + tc + c4);
        s[rr][c4] = v.x; s[rr][c4 + 1] = v.y; s[rr][c4 + 2] = v.z; s[rr][c4 + 3] = v.w;
    }
    __syncthreads();
#pragma unroll
    for (int rr = r; rr < 64; rr += 16) {
        ushort4 o;
        o.x = f2bf(s[c4][rr]);     o.y = f2bf(s[c4 + 1][rr]);
        o.z = f2bf(s[c4 + 2][rr]); o.w = f2bf(s[c4 + 3][rr]);
        *(ushort4*)(WT + (long)(tc + rr) * 1024 + tr + c4) = o;
    }
}

// V [N,D] bf16 -> VT [D,N] bf16 per batch (grid.z)
__global__ void v_transpose(const unsigned short* __restrict__ V, unsigned short* __restrict__ VT)
{
    __shared__ unsigned short s[64][65];
    const long boff = (long)blockIdx.z * ND;
    const int tr = blockIdx.x * 64, tc = blockIdx.y * 64;
    const int t = threadIdx.x;
    const int r = t >> 4, c4 = (t & 15) * 4;
#pragma unroll
    for (int rr = r; rr < 64; rr += 16) {
        ushort4 v = *(const ushort4*)(V + boff + (long)(tr + rr) * 1024 + tc + c4);
        s[rr][c4] = v.x; s[rr][c4 + 1] = v.y; s[rr][c4 + 2] = v.z; s[rr][c4 + 3] = v.w;
    }
    __syncthreads();
#pragma unroll
    for (int rr = r; rr < 64; rr += 16) {
        ushort4 o;
        o.x = s[c4][rr];     o.y = s[c4 + 1][rr];
        o.z = s[c4 + 2][rr]; o.w = s[c4 + 3][rr];
        *(ushort4*)(VT + boff + (long)(tc + rr) * 1024 + tr + c4) = o;
    }
}

// sigma[b,n] = 3^(sigmoid(5*(x_row . Ws)) + 1e-5) - 1 ; one wave per row
__global__ void sigma_proj(const float* __restrict__ x, const float* __restrict__ Ws,
                           float* __restrict__ sigma)
{
    const int row  = blockIdx.x * 4 + (threadIdx.x >> 6);
    const int lane = threadIdx.x & 63;
    const float* xr = x + (long)row * 1024;
    float a = 0.f;
    for (int i = lane * 4; i < 1024; i += 256) {
        float4 v = *(const float4*)(xr + i);
        float4 w = *(const float4*)(Ws + i);
        a += v.x * w.x + v.y * w.y + v.z * w.z + v.w * w.w;
    }
#pragma unroll
    for (int o = 32; o; o >>= 1) a += __shfl_down(a, o);
    if (lane == 0) {
        float s = 1.f / (1.f + __expf(-5.f * a)) + 1e-5f;
        s = exp2f(s * 1.5849625007211562f) - 1.f;   // 3^s - 1
        sigma[row] = s;
    }
}

// softmax over batch dim: for each (n,m), across the 8 batches
__global__ void softmax_batch(const float* __restrict__ scores, unsigned short* __restrict__ S)
{
    const long idx = (long)blockIdx.x * 256 + threadIdx.x;  // < NN
    float v[8], m = -1e30f;
#pragma unroll
    for (int b = 0; b < 8; ++b) { v[b] = scores[(long)b * NN + idx]; m = fmaxf(m, v[b]); }
    float sum = 0.f;
#pragma unroll
    for (int b = 0; b < 8; ++b) { v[b] = __expf(v[b] - m); sum += v[b]; }
    const float inv = 1.f / sum;
#pragma unroll
    for (int b = 0; b < 8; ++b) S[(long)b * NN + idx] = f2bf(v[b] * inv);
}

// rowsum[b,i] = inv_norm * sum_j exp(-0.5*((i-j)/sg)^2) ; one wave per row
__global__ void prior_rowsum(const float* __restrict__ sigma, float* __restrict__ rowsum)
{
    const int row  = blockIdx.x * 4 + (threadIdx.x >> 6);
    const int lane = threadIdx.x & 63;
    const int i = row & 1023;
    const float sg = sigma[row];
    const float c = -0.5f / (sg * sg);
    float a = 0.f;
    for (int j = lane; j < 1024; j += 64) {
        float d = (float)(i - j);
        a += __expf(c * d * d);
    }
#pragma unroll
    for (int o = 32; o; o >>= 1) a += __shfl_down(a, o);
    if (lane == 0) rowsum[row] = (0.3989422804014327f / sg) * a;
}

__global__ void batch_reduce(const float* __restrict__ rowsum, float* __restrict__ batchsum)
{
    __shared__ float s[256];
    const int b = blockIdx.x, t = threadIdx.x;
    float a = 0.f;
    for (int i = t; i < 1024; i += 256) a += rowsum[b * 1024 + i];
    s[t] = a; __syncthreads();
    for (int o = 128; o; o >>= 1) { if (t < o) s[t] += s[t + o]; __syncthreads(); }
    if (t == 0) batchsum[b] = s[0];
}

__global__ void prior_write(const float* __restrict__ sigma, const float* __restrict__ batchsum,
                            float* __restrict__ P)
{
    const long idx = (long)blockIdx.x * 256 + threadIdx.x;   // < B*NN
    const int b   = (int)(idx >> 20);
    const int rem = (int)(idx & (NN - 1));
    const int i = rem >> 10;
    const int j = rem & 1023;
    const float sg = sigma[(b << 10) + i];
    const float d = (float)(i - j);
    const float g = (0.3989422804014327f / sg) * __expf((-0.5f / (sg * sg)) * d * d);
    P[idx] = g / batchsum[b];
}

// ---------------------------------------------------------------------------
extern "C" void kernel_launch(void* const* d_in, const int* in_sizes, int n_in,
                              void* d_out, int out_size, void* d_ws, size_t ws_size,
                              hipStream_t stream)
{
    const float* x  = (const float*)d_in[0];
    const float* Wq = (const float*)d_in[1];
    const float* Wk = (const float*)d_in[2];
    const float* Wv = (const float*)d_in[3];
    const float* Ws = (const float*)d_in[4];
    float* Zout = (float*)d_out;
    float* Pout = Zout + (long)BATCH * ND;

    char* base = (char*)d_ws;
    size_t off = 0;
    auto alloc = [&](size_t bytes) {
        void* p = base + off;
        off = (off + bytes + 255) & ~(size_t)255;
        return p;
    };
    unsigned short* xh  = (unsigned short*)alloc(BATCH * ND * 2);  // [0, 16.78M)
    unsigned short* WqT = (unsigned short*)alloc(NN * 2);
    unsigned short* WkT = (unsigned short*)alloc(NN * 2);
    unsigned short* WvT = (unsigned short*)alloc(NN * 2);
    unsigned short* Vh  = (unsigned short*)alloc(BATCH * ND * 2);  // ends 39.85M
    unsigned short* Qh  = (unsigned short*)alloc(BATCH * ND * 2);
    unsigned short* Kh  = (unsigned short*)alloc(BATCH * ND * 2);
    unsigned short* VTh = (unsigned short*)alloc(BATCH * ND * 2);
    float* sigma    = (float*)alloc(BATCH * SEQ * 4);
    float* rowsum   = (float*)alloc(BATCH * SEQ * 4);
    float* batchsum = (float*)alloc(64);
    // reuse: scores (f32, 33.55MB) overlays xh+WT+Vh (dead by then);
    //        S (bf16) overlays Qh (dead after scores GEMM)
    float*          scores = (float*)xh;
    unsigned short* Sh     = Qh;

    // 1. convert x -> bf16
    cvt_x_bf16<<<8192, 256, 0, stream>>>(x, xh);
    // 2. weights: transpose + convert
    wt_cvt_transpose<<<dim3(16, 16), 256, 0, stream>>>(Wq, WqT);
    wt_cvt_transpose<<<dim3(16, 16), 256, 0, stream>>>(Wk, WkT);
    wt_cvt_transpose<<<dim3(16, 16), 256, 0, stream>>>(Wv, WvT);
    // 3. sigma projection + transform (fp32 exact)
    sigma_proj<<<2048, 256, 0, stream>>>(x, Ws, sigma);
    // 4-6. Q/K/V projections (bf16 MFMA)
    gemm_bt<0><<<dim3(8, 8, 8), 256, 0, stream>>>(xh, WqT, Qh, ND, 0, ND, 1.f);
    gemm_bt<0><<<dim3(8, 8, 8), 256, 0, stream>>>(xh, WkT, Kh, ND, 0, ND, 1.f);
    gemm_bt<0><<<dim3(8, 8, 8), 256, 0, stream>>>(xh, WvT, Vh, ND, 0, ND, 1.f);
    // 7. V -> VT
    v_transpose<<<dim3(16, 16, 8), 256, 0, stream>>>(Vh, VTh);
    // 8. scores = Q K^T / sqrt(D)   (f32 out, overlays dead xh/WT/Vh)
    gemm_bt<1><<<dim3(8, 8, 8), 256, 0, stream>>>(Qh, Kh, scores, ND, ND, NN, 0.03125f);
    // 9. softmax over batch dim -> S (bf16, overlays dead Qh)
    softmax_batch<<<4096, 256, 0, stream>>>(scores, Sh);
    // 10. Z = S V   (f32 out -> d_out)
    gemm_bt<1><<<dim3(8, 8, 8), 256, 0, stream>>>(Sh, VTh, Zout, NN, ND, ND, 1.0f);
    // 11-13. prior P (fp32 exact, deterministic reduction)
    prior_rowsum<<<2048, 256, 0, stream>>>(sigma, rowsum);
    batch_reduce<<<8, 256, 0, stream>>>(rowsum, batchsum);
    prior_write<<<32768, 256, 0, stream>>>(sigma, batchsum, Pout);
}

// Round 2
// 166.352 us; speedup vs baseline: 1.2259x; 1.2259x over previous
//
#include <hip/hip_runtime.h>

// AnomalyAttention forward, MI355X gfx950.
// B=8, N=1024, D=1024. Out = [Z (8*1024*1024 f32), P (8*1024*1024 f32)].
// Round 2: 8-phase-style pipelined GEMM (128x256 tile, BK=64, counted vmcnt,
// XOR-swizzled LDS, setprio), QK fused, VT computed directly, scores scratch
// overlays Pout. Workspace ~74 MB.

typedef __attribute__((ext_vector_type(8))) short bf16x8;
typedef __attribute__((ext_vector_type(4))) float f32x4;
typedef unsigned short ushort_t;

#define DI __device__ __forceinline__

constexpr int  SEQ   = 1024;
constexpr long NN    = 1024L * 1024L;
constexpr long ND    = 1024L * 1024L;

DI ushort_t f2bf(float f) {  // round-to-nearest-even f32 -> bf16 bits
    unsigned int u = __float_as_uint(f);
    u = u + 0x7fffu + ((u >> 16) & 1u);
    return (ushort_t)(u >> 16);
}

// ---------------------------------------------------------------------------
// Pipelined GEMM: C[M,N] = A[M,K=1024] * Bt[N,K=1024]^T, bf16 in, fp32 acc.
// Tile 128x256, BK=64, 8 waves (2M x 4N), per-wave 64x64 (4x4 16x16x32 frags).
// LDS: 2 buffers x (A[128][64] + B[256][64]) = 96 KB, XOR-swizzled
//   (byte ^= (row&7)<<4), staged via global_load_lds with inverse-swizzled
//   global source (rule #21: linear dest + swizzled source + swizzled read).
// Schedule per K-tile t (2 phases):
//   P1: ds_read a[2][4]+b[2][0..1] (12); stage (t+1).B halves -> buf^1;
//       barrier; lgkmcnt(0); setprio(1); 16 MFMA (n0-1); setprio(0); barrier
//   P2: ds_read b[2][2..3] (4); stage (t+2).A halves -> buf;
//       barrier; lgkmcnt(0); vmcnt(2); setprio(1); 16 MFMA (n2-3); barrier
// Safety: region reads drained (lgkm+barrier) >=1 barrier before overwrite;
// vmcnt(2) leaves only the two (t+2).A loads outstanding => tile t+1 landed.
// ---------------------------------------------------------------------------
template <int OUT_BF16>
__global__ __launch_bounds__(512, 2)
void gemm8p(const ushort_t* __restrict__ A, const ushort_t* __restrict__ B,
            void* __restrict__ Cout, int ldA, int ldB, int ldC,
            long sA, long sB, long sC, float scale)
{
    __shared__ ushort_t lds[2][24576];   // per buf: A 8192 + B 16384 ushorts
    constexpr int B_OFF = 8192;

    const int tid  = threadIdx.x;
    const int wave = tid >> 6;
    const int lane = tid & 63;
    const int wm   = wave >> 2;   // 0..1
    const int wn   = wave & 3;    // 0..3
    const int gm   = blockIdx.x * 128;
    const int gn   = blockIdx.y * 256;
    const ushort_t* Ab = A + (long)blockIdx.z * sA;
    const ushort_t* Bb = B + (long)blockIdx.z * sB;

    // staging: thread t loads 16B; within a 64-row slice: row=tid>>3,
    // swizzled source col chunk = (tid&7) ^ (row&7)
    const int  srow = tid >> 3;
    const int  scol = 8 * ((tid & 7) ^ (srow & 7));
    const int  sdst = wave * 512;   // wave-uniform LDS dest offset (ushorts)

    auto stageA = [&](int t, int d, int h) {
        const ushort_t* src = Ab + (long)(gm + h * 64 + srow) * ldA + t * 64 + scol;
        __builtin_amdgcn_global_load_lds(
            (const __attribute__((address_space(1))) void*)src,
            (__attribute__((address_space(3))) void*)(&lds[d][h * 4096 + sdst]),
            16, 0, 0);
    };
    auto stageB = [&](int t, int d, int h, int j) {
        const ushort_t* src = Bb + (long)(gn + h * 128 + j * 64 + srow) * ldB + t * 64 + scol;
        __builtin_amdgcn_global_load_lds(
            (const __attribute__((address_space(1))) void*)src,
            (__attribute__((address_space(3))) void*)(&lds[d][B_OFF + h * 8192 + j * 4096 + sdst]),
            16, 0, 0);
    };

    // fragment read addressing: row = base + (lane&15); swizzled col bytes
    const int arow = wm * 64 + (lane & 15);
    const int brow = wn * 64 + (lane & 15);
    const int cs0 = (((lane >> 4) * 16) ^ ((lane & 7) << 4)) >> 1;        // ks=0, ushorts
    const int cs1 = ((64 + (lane >> 4) * 16) ^ ((lane & 7) << 4)) >> 1;   // ks=1

    f32x4 acc[4][4];
#pragma unroll
    for (int m = 0; m < 4; ++m)
#pragma unroll
        for (int n = 0; n < 4; ++n) acc[m][n] = (f32x4){0.f, 0.f, 0.f, 0.f};

    // prologue: tile0 full -> buf0; tile1 A-halves -> buf1
    stageA(0, 0, 0); stageA(0, 0, 1);
    stageB(0, 0, 0, 0); stageB(0, 0, 0, 1); stageB(0, 0, 1, 0); stageB(0, 0, 1, 1);
    stageA(1, 1, 0); stageA(1, 1, 1);
    asm volatile("s_waitcnt vmcnt(2)" ::: "memory");
    __builtin_amdgcn_s_barrier();
    __builtin_amdgcn_sched_barrier(0);

    for (int t = 0; t < 16; ++t) {
        const int cur = t & 1;
        const ushort_t* la = &lds[cur][0];
        const ushort_t* lb = &lds[cur][B_OFF];

        bf16x8 a[2][4], b[2][4];
        // ---- phase 1 ----
#pragma unroll
        for (int mi = 0; mi < 4; ++mi) {
            a[0][mi] = *(const bf16x8*)&la[(arow + mi * 16) * 64 + cs0];
            a[1][mi] = *(const bf16x8*)&la[(arow + mi * 16) * 64 + cs1];
        }
#pragma unroll
        for (int ni = 0; ni < 2; ++ni) {
            b[0][ni] = *(const bf16x8*)&lb[(brow + ni * 16) * 64 + cs0];
            b[1][ni] = *(const bf16x8*)&lb[(brow + ni * 16) * 64 + cs1];
        }
        if (t < 15) {
            stageB(t + 1, cur ^ 1, 0, 0); stageB(t + 1, cur ^ 1, 0, 1);
            stageB(t + 1, cur ^ 1, 1, 0); stageB(t + 1, cur ^ 1, 1, 1);
        }
        __builtin_amdgcn_s_barrier();
        asm volatile("s_waitcnt lgkmcnt(0)" ::: "memory");
        __builtin_amdgcn_sched_barrier(0);
        __builtin_amdgcn_s_setprio(1);
#pragma unroll
        for (int mi = 0; mi < 4; ++mi)
#pragma unroll
            for (int ni = 0; ni < 2; ++ni) {
                acc[mi][ni] = __builtin_amdgcn_mfma_f32_16x16x32_bf16(a[0][mi], b[0][ni], acc[mi][ni], 0, 0, 0);
                acc[mi][ni] = __builtin_amdgcn_mfma_f32_16x16x32_bf16(a[1][mi], b[1][ni], acc[mi][ni], 0, 0, 0);
            }
        __builtin_amdgcn_s_setprio(0);
        __builtin_amdgcn_s_barrier();
        __builtin_amdgcn_sched_barrier(0);

        // ---- phase 2 ----
#pragma unroll
        for (int ni = 2; ni < 4; ++ni) {
            b[0][ni] = *(const bf16x8*)&lb[(brow + ni * 16) * 64 + cs0];
            b[1][ni] = *(const bf16x8*)&lb[(brow + ni * 16) * 64 + cs1];
        }
        if (t < 14) { stageA(t + 2, cur, 0); stageA(t + 2, cur, 1); }
        __builtin_amdgcn_s_barrier();
        asm volatile("s_waitcnt lgkmcnt(0)" ::: "memory");
        if (t < 14) asm volatile("s_waitcnt vmcnt(2)" ::: "memory");
        else        asm volatile("s_waitcnt vmcnt(0)" ::: "memory");
        __builtin_amdgcn_sched_barrier(0);
        __builtin_amdgcn_s_setprio(1);
#pragma unroll
        for (int mi = 0; mi < 4; ++mi)
#pragma unroll
            for (int ni = 2; ni < 4; ++ni) {
                acc[mi][ni] = __builtin_amdgcn_mfma_f32_16x16x32_bf16(a[0][mi], b[0][ni], acc[mi][ni], 0, 0, 0);
                acc[mi][ni] = __builtin_amdgcn_mfma_f32_16x16x32_bf16(a[1][mi], b[1][ni], acc[mi][ni], 0, 0, 0);
            }
        __builtin_amdgcn_s_setprio(0);
        __builtin_amdgcn_s_barrier();
        __builtin_amdgcn_sched_barrier(0);
    }

    // epilogue. C/D layout (verified): col = lane&15, row = (lane>>4)*4 + r
    if (OUT_BF16) {
        // stage through LDS for coalesced 16B stores
        ushort_t* el = &lds[0][0];   // [128][256] ushort = 64 KB
#pragma unroll
        for (int mi = 0; mi < 4; ++mi)
#pragma unroll
            for (int ni = 0; ni < 4; ++ni)
#pragma unroll
                for (int r = 0; r < 4; ++r)
                    el[(wm * 64 + mi * 16 + (lane >> 4) * 4 + r) * 256 +
                       wn * 64 + ni * 16 + (lane & 15)] = f2bf(acc[mi][ni][r] * scale);
        __builtin_amdgcn_s_barrier();
        ushort_t* C = (ushort_t*)Cout + (long)blockIdx.z * sC;
#pragma unroll
        for (int rr = 0; rr < 8; ++rr) {
            const int row = rr * 16 + (tid >> 5);
            const int col = (tid & 31) * 8;
            *(bf16x8*)&C[(long)(gm + row) * ldC + gn + col] =
                *(const bf16x8*)&el[row * 256 + col];
        }
    } else {
        float* C = (float*)Cout + (long)blockIdx.z * sC;
#pragma unroll
        for (int mi = 0; mi < 4; ++mi)
#pragma unroll
            for (int ni = 0; ni < 4; ++ni)
#pragma unroll
                for (int r = 0; r < 4; ++r)
                    C[(long)(gm + wm * 64 + mi * 16 + (lane >> 4) * 4 + r) * ldC +
                      gn + wn * 64 + ni * 16 + (lane & 15)] = acc[mi][ni][r] * scale;
    }
}

// ---------------------------------------------------------------------------
// elementwise / helper kernels
// ---------------------------------------------------------------------------

// x -> bf16 AND sigma = 3^(sigmoid(5*(x.Ws))+1e-5)-1 in one pass (one wave/row)
__global__ void cvt_x_sigma(const float* __restrict__ x, const float* __restrict__ Ws,
                            ushort_t* __restrict__ xh, float* __restrict__ sigma)
{
    const int row  = blockIdx.x * 4 + (threadIdx.x >> 6);
    const int lane = threadIdx.x & 63;
    const float* xr = x + (long)row * 1024;
    float dot = 0.f;
#pragma unroll
    for (int it = 0; it < 4; ++it) {
        const int i = it * 256 + lane * 4;
        float4 v = *(const float4*)(xr + i);
        float4 w = *(const float4*)(Ws + i);
        dot += v.x * w.x + v.y * w.y + v.z * w.z + v.w * w.w;
        ushort4 o;
        o.x = f2bf(v.x); o.y = f2bf(v.y); o.z = f2bf(v.z); o.w = f2bf(v.w);
        *(ushort4*)(xh + (long)row * 1024 + i) = o;
    }
#pragma unroll
    for (int o = 32; o; o >>= 1) dot += __shfl_down(dot, o);
    if (lane == 0) {
        float s = 1.f / (1.f + __expf(-5.f * dot)) + 1e-5f;
        sigma[row] = exp2f(s * 1.5849625007211562f) - 1.f;   // 3^s - 1
    }
}

// all three weights: W [D,D] f32 -> WT bf16 (WT[n][k] = W[k][n]); z selects
__global__ void wt_all(const float* __restrict__ Wq, const float* __restrict__ Wk,
                       const float* __restrict__ Wv,
                       ushort_t* __restrict__ WqkT, ushort_t* __restrict__ WvT)
{
    const float* W = blockIdx.z == 0 ? Wq : (blockIdx.z == 1 ? Wk : Wv);
    ushort_t* WT = (blockIdx.z == 2) ? WvT : (WqkT + (long)blockIdx.z * 1024 * 1024);
    __shared__ float s[64][65];
    const int tr = blockIdx.x * 64, tc = blockIdx.y * 64;
    const int t = threadIdx.x;
    const int r = t >> 4, c4 = (t & 15) * 4;
#pragma unroll
    for (int rr = r; rr < 64; rr += 16) {
        float4 v = *(const float4*)(W + (long)(tr + rr) * 1024 + tc + c4);
        s[rr][c4] = v.x; s[rr][c4 + 1] = v.y; s[rr][c4 + 2] = v.z; s[rr][c4 + 3] = v.w;
    }
    __syncthreads();
#pragma unroll
    for (int rr = r; rr < 64; rr += 16) {
        ushort4 o;
        o.x = f2bf(s[c4][rr]);     o.y = f2bf(s[c4 + 1][rr]);
        o.z = f2bf(s[c4 + 2][rr]); o.w = f2bf(s[c4 + 3][rr]);
        *(ushort4*)(WT + (long)(tc + rr) * 1024 + tr + c4) = o;
    }
}

// softmax over batch dim (8 values, stride NN)
__global__ void softmax_batch(const float* __restrict__ scores, ushort_t* __restrict__ S)
{
    const long idx = (long)blockIdx.x * 256 + threadIdx.x;
    float v[8], m = -1e30f;
#pragma unroll
    for (int b = 0; b < 8; ++b) { v[b] = scores[(long)b * NN + idx]; m = fmaxf(m, v[b]); }
    float sum = 0.f;
#pragma unroll
    for (int b = 0; b < 8; ++b) { v[b] = __expf(v[b] - m); sum += v[b]; }
    const float inv = 1.f / sum;
#pragma unroll
    for (int b = 0; b < 8; ++b) S[(long)b * NN + idx] = f2bf(v[b] * inv);
}

__global__ void prior_rowsum(const float* __restrict__ sigma, float* __restrict__ rowsum)
{
    const int row  = blockIdx.x * 4 + (threadIdx.x >> 6);
    const int lane = threadIdx.x & 63;
    const int i = row & 1023;
    const float sg = sigma[row];
    const float c = -0.5f / (sg * sg);
    float a = 0.f;
    for (int j = lane; j < 1024; j += 64) {
        float d = (float)(i - j);
        a += __expf(c * d * d);
    }
#pragma unroll
    for (int o = 32; o; o >>= 1) a += __shfl_down(a, o);
    if (lane == 0) rowsum[row] = (0.3989422804014327f / sg) * a;
}

__global__ void batch_reduce(const float* __restrict__ rowsum, float* __restrict__ batchsum)
{
    __shared__ float s[256];
    const int b = blockIdx.x, t = threadIdx.x;
    float a = 0.f;
    for (int i = t; i < 1024; i += 256) a += rowsum[b * 1024 + i];
    s[t] = a; __syncthreads();
    for (int o = 128; o; o >>= 1) { if (t < o) s[t] += s[t + o]; __syncthreads(); }
    if (t == 0) batchsum[b] = s[0];
}

__global__ void prior_write(const float* __restrict__ sigma, const float* __restrict__ batchsum,
                            float* __restrict__ P)
{
    const long idx = (long)blockIdx.x * 256 + threadIdx.x;
    const int b   = (int)(idx >> 20);
    const int rem = (int)(idx & (NN - 1));
    const int i = rem >> 10;
    const int j = rem & 1023;
    const float sg = sigma[(b << 10) + i];
    const float d = (float)(i - j);
    const float g = (0.3989422804014327f / sg) * __expf((-0.5f / (sg * sg)) * d * d);
    P[idx] = g / batchsum[b];
}

// ---------------------------------------------------------------------------
extern "C" void kernel_launch(void* const* d_in, const int* in_sizes, int n_in,
                              void* d_out, int out_size, void* d_ws, size_t ws_size,
                              hipStream_t stream)
{
    const float* x  = (const float*)d_in[0];
    const float* Wq = (const float*)d_in[1];
    const float* Wk = (const float*)d_in[2];
    const float* Wv = (const float*)d_in[3];
    const float* Ws = (const float*)d_in[4];
    float* Zout = (float*)d_out;
    float* Pout = Zout + 8 * ND;

    char* base = (char*)d_ws;
    size_t off = 0;
    auto alloc = [&](size_t bytes) {
        void* p = base + off;
        off = (off + bytes + 255) & ~(size_t)255;
        return p;
    };
    ushort_t* xh    = (ushort_t*)alloc(8192L * 1024 * 2);   // 16.78 MB
    ushort_t* WqkT  = (ushort_t*)alloc(2048L * 1024 * 2);   //  4.19 MB
    ushort_t* WvT   = (ushort_t*)alloc(1024L * 1024 * 2);   //  2.10 MB
    ushort_t* QKh   = (ushort_t*)alloc(8192L * 2048 * 2);   // 33.55 MB
    ushort_t* VTall = (ushort_t*)alloc(1024L * 8192 * 2);   // 16.78 MB
    float* sigma    = (float*)alloc(8192 * 4);
    float* rowsum   = (float*)alloc(8192 * 4);
    float* batchsum = (float*)alloc(64);
    // overlays: scores (f32) -> Pout half of d_out (dead until prior_write);
    //           S (bf16)     -> xh (dead after VT gemm)
    float*    scores = Pout;
    ushort_t* Sh     = xh;

    // 1. x -> bf16 + sigma (fused)
    cvt_x_sigma<<<2048, 256, 0, stream>>>(x, Ws, xh, sigma);
    // 2. all weight transposes (Wq,Wk stacked; Wv separate)
    wt_all<<<dim3(16, 16, 3), 256, 0, stream>>>(Wq, Wk, Wv, WqkT, WvT);
    // 3. [Q|K] = x @ [Wq|Wk]   (M=8192, N=2048) -> QKh ld 2048
    gemm8p<1><<<dim3(64, 8, 1), 512, 0, stream>>>(
        xh, WqkT, QKh, 1024, 1024, 2048, 0, 0, 0, 1.f);
    // 4. VT = Wv^T x^T         (M=1024, N=8192) -> VTall ld 8192
    gemm8p<1><<<dim3(8, 32, 1), 512, 0, stream>>>(
        WvT, xh, VTall, 1024, 1024, 8192, 0, 0, 0, 1.f);
    // 5. scores = Q K^T / 32   (per batch, f32 -> Pout scratch)
    gemm8p<0><<<dim3(8, 4, 8), 512, 0, stream>>>(
        QKh, QKh + 1024, scores, 2048, 2048, 1024,
        1024L * 2048, 1024L * 2048, NN, 0.03125f);
    // 6. softmax over batch -> S (bf16, overlays xh)
    softmax_batch<<<4096, 256, 0, stream>>>(scores, Sh);
    // 7. Z = S V               (per batch, f32 -> d_out)
    gemm8p<0><<<dim3(8, 4, 8), 512, 0, stream>>>(
        Sh, VTall, Zout, 1024, 8192, 1024,
        NN, 1024, ND, 1.f);
    // 8-10. prior P (fp32 exact, deterministic)
    prior_rowsum<<<2048, 256, 0, stream>>>(sigma, rowsum);
    batch_reduce<<<8, 256, 0, stream>>>(rowsum, batchsum);
    prior_write<<<32768, 256, 0, stream>>>(sigma, batchsum, Pout);
}